// Round 7
// baseline (559.523 us; speedup 1.0000x reference)
//
#include <hip/hip_runtime.h>
#include <hip/hip_bf16.h>

// ---------------------------------------------------------------------------
// GAT (2 GATConv + 5-layer MLP), MI355X.
// R4: bf16 hi/lo planes end-to-end, split-bf16 MFMA (3 terms), fused el/er.
// R12: prep_kernel fuses conv+convw+hist; scatter reuses cnt via atomicSub.
// R16: gemm/mlp staging -> global_load_lds(16B) + both-sides XOR swizzle
//     (-46 us, verified, 524 us).
// R17 (FAILED): both-layer fp8 gather, absmax 1.86e-5 > 1.495e-5.
// R18: mixed precision (L1 fp8 / L2 bf16) PASSED 1.31e-5, dur unchanged:
//     agg not bytes-bound, not line-request-bound.
// R19 (REGRESSED): 8-row gather; confounded (occupancy -36%, 4x chain).
// R20: direct exp + 8-deep batching + 2 nodes/block barrier-free (-3.5 us;
//     agg2 97.2 us @ 3.05 TB/s). Accounting: agg1-fp8 still ~100 @ 1.5 TB/s.
// R21: PAIR-LOADS. One wave-load covers 2 edges (lane owns a 4-feature quad;
//     slot = l>>5 picks even/odd edge). Wave-load count halves at constant
//     occupancy, +2 FMA chain, same lines/bytes; (s,w) broadcast via shfl
//     (no loop LDS); one shfl_xor(32) merges slots. Clean A/B: if agg is
//     instruction-paced both aggs -> ~75; if line-paced agg2 stays 97.
//     (R21 bench attempt hit an infra failure — resubmitted unchanged.)
// ---------------------------------------------------------------------------

typedef __attribute__((ext_vector_type(8))) short short8;   // 8 bf16 = 4 VGPR
typedef __attribute__((ext_vector_type(4))) float float4v;  // MFMA C/D
typedef __attribute__((ext_vector_type(2))) float floatx2;

__device__ inline short f2bf(float x) {
    union { float f; unsigned u; } v; v.f = x;
    unsigned r = v.u + 0x7FFFu + ((v.u >> 16) & 1u);   // RNE
    return (short)(r >> 16);
}
__device__ inline float bf2f(short b) {
    union { float f; unsigned u; } v;
    v.u = ((unsigned)(unsigned short)b) << 16;
    return v.f;
}
__device__ inline short8 zero8() { short8 z = {0,0,0,0,0,0,0,0}; return z; }

// ---- fp8 e4m3 pack/unpack (HW conversions on gfx950; exact SW fallback) ----
#if __has_builtin(__builtin_amdgcn_cvt_pk_fp8_f32)
__device__ inline unsigned short pk2fp8(float a, float b) {
    return (unsigned short)(__builtin_amdgcn_cvt_pk_fp8_f32(a, b, 0, false) & 0xFFFF);
}
#else
__device__ inline unsigned char f2fp8_1(float x) {
    union { float f; unsigned u; } v; v.f = x;
    unsigned s = (v.u >> 24) & 0x80u;
    unsigned au = v.u & 0x7FFFFFFFu;
    if (au >= 0x43E00000u) return (unsigned char)(s | 0x7E);   // saturate 448
    if (au < 0x3C800000u) {                                    // subnormal
        union { float f; unsigned u; } a; a.u = au;
        int k = (int)(a.f * 512.0f + 0.5f);
        if (k > 7) return (unsigned char)(s | 0x08);
        return (unsigned char)(s | (unsigned)k);
    }
    unsigned r = au + 0x0007FFFFu + ((au >> 20) & 1u);         // RNE @bit20
    unsigned e = (r >> 23) - 120u;
    unsigned m = (r >> 20) & 7u;
    if (e >= 15u && m >= 7u) { e = 15u; m = 6u; }              // avoid NaN enc
    return (unsigned char)(s | (e << 3) | m);
}
__device__ inline unsigned short pk2fp8(float a, float b) {
    return (unsigned short)f2fp8_1(a) | ((unsigned short)f2fp8_1(b) << 8);
}
#endif

#if __has_builtin(__builtin_amdgcn_cvt_pk_f32_fp8)
__device__ inline floatx2 unpk2fp8(unsigned short p) {
    return __builtin_amdgcn_cvt_pk_f32_fp8((int)p, false);
}
#else
__device__ inline float fp8_1_2f(unsigned char b) {
    unsigned s = b >> 7, e = (b >> 3) & 15u, m = b & 7u;
    float v = (e == 0) ? (float)m * 0.001953125f
                       : (float)(8u + m) * exp2f((float)((int)e - 10));
    return s ? -v : v;
}
__device__ inline floatx2 unpk2fp8(unsigned short p) {
    floatx2 r; r.x = fp8_1_2f((unsigned char)(p & 0xFF));
    r.y = fp8_1_2f((unsigned char)(p >> 8)); return r;
}
#endif

// async global->LDS, 16 B per lane (dest = wave-uniform base + lane*16)
__device__ __forceinline__ void gl_lds16(const short* g, short* l) {
    __builtin_amdgcn_global_load_lds(
        (const __attribute__((address_space(1))) void*)g,
        (__attribute__((address_space(3))) void*)l,
        16, 0, 0);
}

// XOR swizzle for 16B slots within a 64B row (8-way -> 2-way, free per m136).
#define SW(r) ((((r) >> 2) ^ (r)) & 3)

#define BM 128
#define BN 128
#define BK 32
#define MSTR 136   // act row stride in shorts (272 B = 17x16B, breaks pow2)
#define MROWS 64   // mlp_fused rows per block

// ---------------------------------------------------------------------------
// Fused prep: [0, cb) conv_split | [cb, cb+wb) weight transpose | rest hist.
__global__ void prep_kernel(
    const float* __restrict__ in_feat, short* __restrict__ P1h,
    short* __restrict__ P1l, int n4, int cb, int wb,
    const int* __restrict__ dst, int* __restrict__ cnt, int E,
    const float* __restrict__ w1, const float* __restrict__ w2,
    const float* __restrict__ m1, const float* __restrict__ m2,
    const float* __restrict__ m3, const float* __restrict__ m4,
    const float* __restrict__ w5,
    short* __restrict__ w1h, short* __restrict__ w1l,
    short* __restrict__ w2h, short* __restrict__ w2l,
    short* __restrict__ m1h, short* __restrict__ m1l,
    short* __restrict__ m2h, short* __restrict__ m2l,
    short* __restrict__ m3h, short* __restrict__ m3l,
    short* __restrict__ m4h, short* __restrict__ m4l,
    short* __restrict__ w5h, short* __restrict__ w5l)
{
    int blk = blockIdx.x;
    if (blk < cb) {
        int i = blk * 256 + threadIdx.x;
        if (i >= n4) return;
        float4 v = *(const float4*)(in_feat + (size_t)i * 4);
        float xs[4] = {v.x, v.y, v.z, v.w};
        short hs[4], ls[4];
        #pragma unroll
        for (int j = 0; j < 4; ++j) {
            hs[j] = f2bf(xs[j]);
            ls[j] = f2bf(xs[j] - bf2f(hs[j]));
        }
        *(uint2*)(P1h + (size_t)i * 4) = *(uint2*)hs;
        *(uint2*)(P1l + (size_t)i * 4) = *(uint2*)ls;
    } else if (blk < cb + wb) {
        int j = (blk - cb) * 256 + threadIdx.x;
        const float* src; short* th; short* tl; int Nc, base;
        if      (j < 49152)  { src = w1; th = w1h; tl = w1l; Nc = 384; base = 0; }
        else if (j < 98304)  { src = w2; th = w2h; tl = w2l; Nc = 384; base = 49152; }
        else if (j < 114688) { src = m1; th = m1h; tl = m1l; Nc = 128; base = 98304; }
        else if (j < 131072) { src = m2; th = m2h; tl = m2l; Nc = 128; base = 114688; }
        else if (j < 147456) { src = m3; th = m3h; tl = m3l; Nc = 128; base = 131072; }
        else if (j < 163840) { src = m4; th = m4h; tl = m4l; Nc = 128; base = 147456; }
        else if (j < 164608) { src = w5; th = w5h; tl = w5l; Nc = 6;   base = 163840; }
        else return;
        int i = j - base;
        int k = i / Nc, c = i - k * Nc;
        float v = src[i];
        short h = f2bf(v);
        th[(size_t)c * 128 + k] = h;
        tl[(size_t)c * 128 + k] = f2bf(v - bf2f(h));
    } else {
        int e = (blk - cb - wb) * 256 + threadIdx.x;
        if (e < E) atomicAdd(&cnt[dst[e]], 1);
    }
}

// ---------------------------------------------------------------------------
// GEMM (GAT layers): C[M x Nc] = A @ W, fused el/er. flags: 1 bias, 2 lrelu,
// 4 el/er, 8 fp32 C, 16 hi plane, 32 lo plane, 64 fp8 C.
__global__ __launch_bounds__(256) void gemm_mfma(
    const short* __restrict__ Ahi, const short* __restrict__ Alo,
    const short* __restrict__ Bth, const short* __restrict__ Btl,
    const float* __restrict__ bias,
    float* __restrict__ Cf, short* __restrict__ Chi, short* __restrict__ Clo,
    unsigned char* __restrict__ Cf8,
    float* __restrict__ el, float* __restrict__ er,
    const float* __restrict__ al, const float* __restrict__ ar,
    int M, int Nc, int flags)
{
    __shared__ short Ah[BM * BK], Al_[BM * BK];
    __shared__ short Bh[BN * BK], Bl_[BN * BK];

    int tid = threadIdx.x, lane = tid & 63, wave = tid >> 6;
    int l15 = lane & 15, q = lane >> 4;
    int rowBase = blockIdx.y * BM, colBase = blockIdx.x * BN;

    float4v acc[2][8];
    #pragma unroll
    for (int mt = 0; mt < 2; ++mt)
        #pragma unroll
        for (int nt = 0; nt < 8; ++nt)
            acc[mt][nt] = (float4v){0.f, 0.f, 0.f, 0.f};

    for (int k0 = 0; k0 < 128; k0 += BK) {
        #pragma unroll
        for (int i = 0; i < 2; ++i) {
            int cid = tid + i * 256;             // wave-uniform base + lane
            int r = cid >> 2, sub = cid & 3;
            int gs = (sub ^ SW(r)) * 8;
            size_t ga = (size_t)(rowBase + r) * 128 + k0 + gs;
            size_t gb = (size_t)(colBase + r) * 128 + k0 + gs;
            int ld = cid * 8;
            gl_lds16(Ahi + ga, Ah  + ld);
            gl_lds16(Alo + ga, Al_ + ld);
            gl_lds16(Bth + gb, Bh  + ld);
            gl_lds16(Btl + gb, Bl_ + ld);
        }
        __syncthreads();

        short8 aH[2], aL2[2];
        #pragma unroll
        for (int mt = 0; mt < 2; ++mt) {
            int row = wave * 32 + mt * 16 + l15;
            int off = row * 32 + (q ^ SW(row)) * 8;
            aH[mt]  = *(short8*)&Ah[off];
            aL2[mt] = *(short8*)&Al_[off];
        }
        #pragma unroll
        for (int nt = 0; nt < 8; ++nt) {
            int row = nt * 16 + l15;
            int off = row * 32 + (q ^ SW(row)) * 8;
            short8 bH = *(short8*)&Bh[off];
            short8 bL = *(short8*)&Bl_[off];
            #pragma unroll
            for (int mt = 0; mt < 2; ++mt) {
                acc[mt][nt] = __builtin_amdgcn_mfma_f32_16x16x32_bf16(aH[mt], bH, acc[mt][nt], 0, 0, 0);
                acc[mt][nt] = __builtin_amdgcn_mfma_f32_16x16x32_bf16(aH[mt], bL, acc[mt][nt], 0, 0, 0);
                acc[mt][nt] = __builtin_amdgcn_mfma_f32_16x16x32_bf16(aL2[mt], bH, acc[mt][nt], 0, 0, 0);
            }
        }
        __syncthreads();
    }

    if (flags & 4) {
        const float* alh = al + colBase;
        const float* arh = ar + colBase;
        float pel[2][4] = {}, per_[2][4] = {};
        #pragma unroll
        for (int nt = 0; nt < 8; ++nt) {
            float av = alh[nt * 16 + l15];
            float rv = arh[nt * 16 + l15];
            #pragma unroll
            for (int mt = 0; mt < 2; ++mt)
                #pragma unroll
                for (int i = 0; i < 4; ++i) {
                    pel[mt][i]  += acc[mt][nt][i] * av;
                    per_[mt][i] += acc[mt][nt][i] * rv;
                }
        }
        #pragma unroll
        for (int mask = 1; mask < 16; mask <<= 1)
            #pragma unroll
            for (int mt = 0; mt < 2; ++mt)
                #pragma unroll
                for (int i = 0; i < 4; ++i) {
                    pel[mt][i]  += __shfl_xor(pel[mt][i], mask);
                    per_[mt][i] += __shfl_xor(per_[mt][i], mask);
                }
        if (l15 == 0) {
            #pragma unroll
            for (int mt = 0; mt < 2; ++mt)
                #pragma unroll
                for (int i = 0; i < 4; ++i) {
                    int r = rowBase + wave * 32 + mt * 16 + q * 4 + i;
                    if (r < M) {
                        el[r * 3 + blockIdx.x] = pel[mt][i];
                        er[r * 3 + blockIdx.x] = per_[mt][i];
                    }
                }
        }
    }

    #pragma unroll
    for (int mt = 0; mt < 2; ++mt) {
        #pragma unroll
        for (int nt = 0; nt < 8; ++nt) {
            int c = colBase + nt * 16 + l15;
            bool cok = c < Nc;
            float bv = ((flags & 1) && cok) ? bias[c] : 0.f;
            #pragma unroll
            for (int i = 0; i < 4; ++i) {
                int r = rowBase + wave * 32 + mt * 16 + q * 4 + i;
                float v = acc[mt][nt][i] + bv;
                if (flags & 2) v = (v < 0.f) ? 0.01f * v : v;
                float vn = __shfl_xor(v, 1);      // neighbor (c^1), all lanes
                if (cok && r < M) {
                    size_t idx = (size_t)r * Nc + c;
                    if (flags & 8)  Cf[idx] = v;
                    if (flags & 16) {
                        short hh = f2bf(v);
                        Chi[idx] = hh;
                        if (flags & 32) Clo[idx] = f2bf(v - bf2f(hh));
                    }
                    if ((flags & 64) && !(l15 & 1))
                        *(unsigned short*)(Cf8 + idx) = pk2fp8(v, vn);
                }
            }
        }
    }
}

// ---------------------------------------------------------------------------
// Fused MLP head: 4x (128->128, bias, lrelu) + (128->6, bias) in one kernel.
__global__ __launch_bounds__(256) void mlp_fused(
    const short* __restrict__ Ph, const short* __restrict__ Pl,
    const short* __restrict__ w1h, const short* __restrict__ w1l,
    const short* __restrict__ w2h, const short* __restrict__ w2l,
    const short* __restrict__ w3h, const short* __restrict__ w3l,
    const short* __restrict__ w4h, const short* __restrict__ w4l,
    const short* __restrict__ w5h, const short* __restrict__ w5l,
    const float* __restrict__ b1, const float* __restrict__ b2,
    const float* __restrict__ b3, const float* __restrict__ b4,
    const float* __restrict__ b5,
    float* __restrict__ out, int M)
{
    __shared__ short AH[MROWS * MSTR], AL[MROWS * MSTR];
    __shared__ short WH[128 * BK], WL[128 * BK];

    int tid = threadIdx.x, lane = tid & 63, wave = tid >> 6;
    int l15 = lane & 15, q = lane >> 4;
    int rowBase = blockIdx.x * MROWS;

    #pragma unroll
    for (int s = 0; s < 4; ++s) {
        int idx = tid + s * 256;
        int r = idx >> 4, kq = (idx & 15) * 8;
        int gr = rowBase + r;
        short8 vh = zero8(), vl = zero8();
        if (gr < M) {
            vh = *(const short8*)(Ph + (size_t)gr * 128 + kq);
            vl = *(const short8*)(Pl + (size_t)gr * 128 + kq);
        }
        *(short8*)&AH[r * MSTR + kq] = vh;
        *(short8*)&AL[r * MSTR + kq] = vl;
    }

    const short* Whs[4] = {w1h, w2h, w3h, w4h};
    const short* Wls[4] = {w1l, w2l, w3l, w4l};
    const float* Bss[4] = {b1, b2, b3, b4};

    #pragma unroll
    for (int L = 0; L < 4; ++L) {
        float4v acc[8];
        #pragma unroll
        for (int nt = 0; nt < 8; ++nt)
            acc[nt] = (float4v){0.f, 0.f, 0.f, 0.f};

        for (int k0 = 0; k0 < 128; k0 += BK) {
            #pragma unroll
            for (int i = 0; i < 4; ++i) {          // i<2: hi plane, i>=2: lo
                int c2 = tid + (i & 1) * 256;       // 0..511
                int r = c2 >> 2, sub = c2 & 3;
                int gs = (sub ^ SW(r)) * 8;
                if (i < 2) gl_lds16(Whs[L] + (size_t)r * 128 + k0 + gs, WH + c2 * 8);
                else       gl_lds16(Wls[L] + (size_t)r * 128 + k0 + gs, WL + c2 * 8);
            }
            __syncthreads();
            int offa = (wave * 16 + l15) * MSTR + k0 + q * 8;
            short8 aH  = *(short8*)&AH[offa];
            short8 aL2 = *(short8*)&AL[offa];
            #pragma unroll
            for (int nt = 0; nt < 8; ++nt) {
                int row = nt * 16 + l15;
                int off = row * 32 + (q ^ SW(row)) * 8;
                short8 bH = *(short8*)&WH[off];
                short8 bL = *(short8*)&WL[off];
                acc[nt] = __builtin_amdgcn_mfma_f32_16x16x32_bf16(aH, bH, acc[nt], 0, 0, 0);
                acc[nt] = __builtin_amdgcn_mfma_f32_16x16x32_bf16(aH, bL, acc[nt], 0, 0, 0);
                acc[nt] = __builtin_amdgcn_mfma_f32_16x16x32_bf16(aL2, bH, acc[nt], 0, 0, 0);
            }
            __syncthreads();
        }
        #pragma unroll
        for (int nt = 0; nt < 8; ++nt) {
            int c = nt * 16 + l15;
            float bv = Bss[L][c];
            #pragma unroll
            for (int i = 0; i < 4; ++i) {
                int r = wave * 16 + q * 4 + i;
                float v = acc[nt][i] + bv;
                v = (v < 0.f) ? 0.01f * v : v;
                short hh = f2bf(v);
                AH[r * MSTR + c] = hh;
                AL[r * MSTR + c] = f2bf(v - bf2f(hh));
            }
        }
        __syncthreads();
    }

    float4v acc5 = (float4v){0.f, 0.f, 0.f, 0.f};
    for (int k0 = 0; k0 < 128; k0 += BK) {
        if (tid < 128) {
            int plane = tid >> 6, rem = tid & 63;
            int c = rem >> 2, sub = rem & 3;
            short8 v = zero8();
            if (c < 6)
                v = *(const short8*)((plane ? w5l : w5h) + (size_t)c * 128 + k0 + sub * 8);
            *(short8*)&((plane ? WL : WH)[c * 32 + (sub ^ SW(c)) * 8]) = v;
        }
        __syncthreads();
        int offa = (wave * 16 + l15) * MSTR + k0 + q * 8;
        short8 aH  = *(short8*)&AH[offa];
        short8 aL2 = *(short8*)&AL[offa];
        int offb = l15 * 32 + (q ^ SW(l15)) * 8;
        short8 bH = *(short8*)&WH[offb];
        short8 bL = *(short8*)&WL[offb];
        acc5 = __builtin_amdgcn_mfma_f32_16x16x32_bf16(aH, bH, acc5, 0, 0, 0);
        acc5 = __builtin_amdgcn_mfma_f32_16x16x32_bf16(aH, bL, acc5, 0, 0, 0);
        acc5 = __builtin_amdgcn_mfma_f32_16x16x32_bf16(aL2, bH, acc5, 0, 0, 0);
        __syncthreads();
    }
    if (l15 < 6) {
        float bv = b5[l15];
        #pragma unroll
        for (int i = 0; i < 4; ++i) {
            int r = rowBase + wave * 16 + q * 4 + i;
            if (r < M) out[(size_t)r * 6 + l15] = acc5[i] + bv;
        }
    }
}

// ---------------------------------------------------------------------------
// CSR build (hist lives in prep_kernel)
__global__ __launch_bounds__(1024) void scan_block(const int* __restrict__ cnt,
                                                   int* __restrict__ off,
                                                   int* __restrict__ bsum, int n)
{
    __shared__ int tmp[1024];
    int tid = threadIdx.x;
    int i = blockIdx.x * 1024 + tid;
    int v = (i < n) ? cnt[i] : 0;
    tmp[tid] = v;
    __syncthreads();
    for (int s = 1; s < 1024; s <<= 1) {
        int t = (tid >= s) ? tmp[tid - s] : 0;
        __syncthreads();
        tmp[tid] += t;
        __syncthreads();
    }
    if (i < n) off[i] = tmp[tid] - v;
    if (tid == 1023) bsum[blockIdx.x] = tmp[1023];
}

__global__ void scan_add2(int* __restrict__ off, const int* __restrict__ bsum,
                          int n, int nb)
{
    __shared__ int pre[64];
    int tid = threadIdx.x;
    if (tid < 64) {
        int v = (tid < nb) ? bsum[tid] : 0;
        #pragma unroll
        for (int s = 1; s < 64; s <<= 1) {
            int t = __shfl_up(v, s);
            if (tid >= s) v += t;
        }
        pre[tid] = v;
    }
    __syncthreads();
    int i = blockIdx.x * blockDim.x + tid;
    if (i < n) {
        int chunk = i >> 10;
        off[i] += chunk ? pre[chunk - 1] : 0;
    }
    if (i == 0) off[n] = pre[nb - 1];
}

__global__ void scatter_kernel(const int* __restrict__ src, const int* __restrict__ dst,
                               const int* __restrict__ off, int* __restrict__ cnt,
                               int* __restrict__ csrc, int E)
{
    int e = blockIdx.x * blockDim.x + threadIdx.x;
    if (e < E) {
        int d = dst[e];
        int p = atomicSub(&cnt[d], 1) - 1;
        csrc[off[d] + p] = src[e];
    }
}

// ---------------------------------------------------------------------------
// Fused edge-softmax + weighted gather + bias + lrelu + head-mean.
// R21: 2 nodes/block (384 thr, 6 waves); wave u = (node nl, head).
// PAIR-LOADS: lane l = (slot = l>>5: even/odd edge, fi = l&31: feature quad).
// One wave-load covers 2 edges x 64B/128B segment-halves. (s,w) broadcast
// via shfl (no loop LDS); direct exp; 8-deep load batching (16 edges/batch);
// shfl_xor(32) merges slots; single final den tree + __syncthreads.
template <bool FP8>
__global__ __launch_bounds__(384) void agg_kernel(
    const void* __restrict__ hsrc, const float* __restrict__ el,
    const float* __restrict__ er, const int* __restrict__ off,
    const int* __restrict__ csrc, const float* __restrict__ bias,
    short* __restrict__ outH, short* __restrict__ outL, int N)
{
    constexpr int ROWB = FP8 ? 384 : 768;   // full row bytes
    constexpr int SEGB = ROWB / 3;          // per-head segment bytes

    const unsigned char* hb = (const unsigned char*)hsrc;
    int tid = threadIdx.x;         // 0..383
    int u = tid >> 6;              // wave 0..5
    int nl = u / 3;                // node-local 0/1
    int head = u - nl * 3;         // 0..2
    int l = tid & 63;
    int slot = l >> 5;             // even/odd edge of the pair
    int fi = l & 31;               // feature-quad index (4 features)
    int n = blockIdx.x * 2 + nl;
    bool active = (n < N);

    __shared__ float smS[2][384];

    int beg = 0, deg = 0;
    float erv = 0.f;
    if (active) {
        beg = off[n];
        deg = off[n + 1] - beg;
        erv = er[n * 3 + head];
    }

    const unsigned char* hseg = hb + head * SEGB + fi * (FP8 ? 4 : 8);
    float acc0 = 0.f, acc1 = 0.f, acc2 = 0.f, acc3 = 0.f, denl = 0.f;

    for (int base = 0; base < deg; base += 64) {
        int cnt = min(64, deg - base);
        int s_l = 0; float w = 0.f;
        if (l < cnt) {
            s_l = csrc[beg + base + l];
            float t = el[s_l * 3 + head] + erv;
            t = (t < 0.f) ? 0.2f * t : t;
            w = __expf(t);                 // direct exp: logits bounded
        }
        denl += w;
        for (int q0 = 0; q0 < cnt; q0 += 16) {     // 8 pair-loads = 16 edges
            int sA[8]; float wA[8];
            #pragma unroll
            for (int b = 0; b < 8; ++b) {
                int e = q0 + 2 * b + slot;          // <= 63; pads have w=0,s=0
                sA[b] = __shfl(s_l, e);
                wA[b] = __shfl(w, e);
            }
            if constexpr (FP8) {
                unsigned vA[8];
                #pragma unroll
                for (int b = 0; b < 8; ++b)
                    vA[b] = *(const unsigned*)(hseg + (size_t)sA[b] * ROWB);
                #pragma unroll
                for (int b = 0; b < 8; ++b) {
                    floatx2 f0 = unpk2fp8((unsigned short)(vA[b] & 0xFFFFu));
                    floatx2 f1 = unpk2fp8((unsigned short)(vA[b] >> 16));
                    acc0 += wA[b] * f0.x;
                    acc1 += wA[b] * f0.y;
                    acc2 += wA[b] * f1.x;
                    acc3 += wA[b] * f1.y;
                }
            } else {
                uint2 vA[8];
                #pragma unroll
                for (int b = 0; b < 8; ++b)
                    vA[b] = *(const uint2*)(hseg + (size_t)sA[b] * ROWB);
                #pragma unroll
                for (int b = 0; b < 8; ++b) {
                    union { unsigned u; float f; } g0, g1, g2, g3;
                    g0.u = vA[b].x << 16; g1.u = vA[b].x & 0xffff0000u;
                    g2.u = vA[b].y << 16; g3.u = vA[b].y & 0xffff0000u;
                    acc0 += wA[b] * g0.f;
                    acc1 += wA[b] * g1.f;
                    acc2 += wA[b] * g2.f;
                    acc3 += wA[b] * g3.f;
                }
            }
        }
    }

    // merge even/odd edge slots
    acc0 += __shfl_xor(acc0, 32);
    acc1 += __shfl_xor(acc1, 32);
    acc2 += __shfl_xor(acc2, 32);
    acc3 += __shfl_xor(acc3, 32);

    float den = denl;
    #pragma unroll
    for (int msk = 1; msk < 64; msk <<= 1) den += __shfl_xor(den, msk);
    float r = 1.f / (den + 1e-9f);
    if (deg == 0) r = 0.f;

    if (active && slot == 0) {
        int fb = head * 128 + fi * 4;
        float4 bv = *(const float4*)(bias + fb);
        float v0 = acc0 * r + bv.x; v0 = (v0 < 0.f) ? 0.01f * v0 : v0;
        float v1 = acc1 * r + bv.y; v1 = (v1 < 0.f) ? 0.01f * v1 : v1;
        float v2 = acc2 * r + bv.z; v2 = (v2 < 0.f) ? 0.01f * v2 : v2;
        float v3 = acc3 * r + bv.w; v3 = (v3 < 0.f) ? 0.01f * v3 : v3;
        smS[nl][fb]     = v0;
        smS[nl][fb + 1] = v1;
        smS[nl][fb + 2] = v2;
        smS[nl][fb + 3] = v3;
    }
    __syncthreads();
    if (tid < 128) {
        int mn = tid >> 6;                 // node-local 0/1
        int n2 = blockIdx.x * 2 + mn;
        if (n2 < N) {
            int f0i = (tid & 63) * 2, f1i = f0i + 1;
            float mx = (smS[mn][f0i] + smS[mn][128 + f0i] + smS[mn][256 + f0i]) * (1.0f / 3.0f);
            float my = (smS[mn][f1i] + smS[mn][128 + f1i] + smS[mn][256 + f1i]) * (1.0f / 3.0f);
            short hx = f2bf(mx), lx = f2bf(mx - bf2f(hx));
            short hy = f2bf(my), ly = f2bf(my - bf2f(hy));
            unsigned ph = (unsigned)(unsigned short)hx | ((unsigned)(unsigned short)hy << 16);
            unsigned pl = (unsigned)(unsigned short)lx | ((unsigned)(unsigned short)ly << 16);
            *(unsigned*)(outH + (size_t)n2 * 128 + f0i) = ph;
            *(unsigned*)(outL + (size_t)n2 * 128 + f0i) = pl;
        }
    }
}

// ---------------------------------------------------------------------------
extern "C" void kernel_launch(void* const* d_in, const int* in_sizes, int n_in,
                              void* d_out, int out_size, void* d_ws, size_t ws_size,
                              hipStream_t stream)
{
    const float* in_feat = (const float*)d_in[0];
    const int*   src     = (const int*)d_in[1];
    const int*   dst     = (const int*)d_in[2];
    const float* W1  = (const float*)d_in[3];
    const float* al1 = (const float*)d_in[4];
    const float* ar1 = (const float*)d_in[5];
    const float* b1  = (const float*)d_in[6];
    const float* W2  = (const float*)d_in[7];
    const float* al2 = (const float*)d_in[8];
    const float* ar2 = (const float*)d_in[9];
    const float* b2  = (const float*)d_in[10];
    const float* lw1 = (const float*)d_in[11];
    const float* lb1 = (const float*)d_in[12];
    const float* lw2 = (const float*)d_in[13];
    const float* lb2 = (const float*)d_in[14];
    const float* lw3 = (const float*)d_in[15];
    const float* lb3 = (const float*)d_in[16];
    const float* lw4 = (const float*)d_in[17];
    const float* lb4 = (const float*)d_in[18];
    const float* lw5 = (const float*)d_in[19];
    const float* lb5 = (const float*)d_in[20];

    const int N = in_sizes[0] / 128;   // 50000
    const int E = in_sizes[1];         // 800000

    size_t o = 0;
    auto alloc = [&](size_t bytes) { size_t p = o; o = (o + bytes + 255) & ~(size_t)255; return p; };
    char* ws = (char*)d_ws;
    short* P1h = (short*)(ws + alloc((size_t)N * 128 * 2));
    short* P1l = (short*)(ws + alloc((size_t)N * 128 * 2));
    short* P2h = (short*)(ws + alloc((size_t)N * 128 * 2));
    short* P2l = (short*)(ws + alloc((size_t)N * 128 * 2));
    short* AbH = (short*)(ws + alloc((size_t)N * 384 * 2));          // bf16 gemm out (L2)
    unsigned char* Af8 = (unsigned char*)(ws + alloc((size_t)N * 384)); // fp8 gemm out (L1)
    float* el  = (float*)(ws + alloc((size_t)N * 3 * 4));
    float* er  = (float*)(ws + alloc((size_t)N * 3 * 4));
    int*   cnt  = (int*)(ws + alloc((size_t)N * 4));
    int*   off  = (int*)(ws + alloc((size_t)(N + 1) * 4));
    int*   bsum = (int*)(ws + alloc((size_t)4096));
    int*   csrc = (int*)(ws + alloc((size_t)E * 4));
    short* w1th = (short*)(ws + alloc((size_t)384 * 128 * 2));
    short* w1tl = (short*)(ws + alloc((size_t)384 * 128 * 2));
    short* w2th = (short*)(ws + alloc((size_t)384 * 128 * 2));
    short* w2tl = (short*)(ws + alloc((size_t)384 * 128 * 2));
    short* l1th = (short*)(ws + alloc((size_t)128 * 128 * 2));
    short* l1tl = (short*)(ws + alloc((size_t)128 * 128 * 2));
    short* l2th = (short*)(ws + alloc((size_t)128 * 128 * 2));
    short* l2tl = (short*)(ws + alloc((size_t)128 * 128 * 2));
    short* l3th = (short*)(ws + alloc((size_t)128 * 128 * 2));
    short* l3tl = (short*)(ws + alloc((size_t)128 * 128 * 2));
    short* l4th = (short*)(ws + alloc((size_t)128 * 128 * 2));
    short* l4tl = (short*)(ws + alloc((size_t)128 * 128 * 2));
    short* l5th = (short*)(ws + alloc((size_t)6 * 128 * 2));
    short* l5tl = (short*)(ws + alloc((size_t)6 * 128 * 2));
    (void)ws_size;

    float* out = (float*)d_out;

    // ---- fused prep: conv_split + weight transpose + hist (one launch)
    hipMemsetAsync(cnt, 0, (size_t)N * 4, stream);
    int n4 = N * 128 / 4;
    int cb = (n4 + 255) / 256;
    int wb = (164608 + 255) / 256;
    int hb = (E + 255) / 256;
    prep_kernel<<<cb + wb + hb, 256, 0, stream>>>(
        in_feat, P1h, P1l, n4, cb, wb, dst, cnt, E,
        W1, W2, lw1, lw2, lw3, lw4, lw5,
        w1th, w1tl, w2th, w2tl, l1th, l1tl, l2th, l2tl,
        l3th, l3tl, l4th, l4tl, l5th, l5tl);

    // ---- CSR scan + scatter
    int nb = (N + 1023) / 1024;
    scan_block<<<nb, 1024, 0, stream>>>(cnt, off, bsum, N);
    scan_add2<<<(N + 255) / 256, 256, 0, stream>>>(off, bsum, N, nb);
    scatter_kernel<<<(E + 255) / 256, 256, 0, stream>>>(src, dst, off, cnt, csrc, E);

    int RB = (N + BM - 1) / BM;
    auto gemm = [&](const short* ah, const short* alo, const short* bth, const short* btl,
                    const float* bias, float* cf, short* chi, short* clo,
                    unsigned char* cf8,
                    float* elp, float* erp, const float* alp, const float* arp,
                    int Nc, int flags) {
        dim3 grid((Nc + BN - 1) / BN, RB);
        gemm_mfma<<<grid, 256, 0, stream>>>(ah, alo, bth, btl, bias, cf, chi, clo, cf8,
                                            elp, erp, alp, arp, N, Nc, flags);
    };

    int AGB = (N + 1) / 2;
    // ---- GAT layer 1 (fp8 h for gather — error attenuated by downstream net)
    gemm(P1h, P1l, w1th, w1tl, nullptr, nullptr, nullptr, nullptr, Af8, el, er, al1, ar1, 384, 4 | 64);
    agg_kernel<true><<<AGB, 384, 0, stream>>>(Af8, el, er, off, csrc, b1, P2h, P2l, N);

    // ---- GAT layer 2 (bf16 h for gather — precision-critical)
    gemm(P2h, P2l, w2th, w2tl, nullptr, nullptr, AbH, nullptr, nullptr, el, er, al2, ar2, 384, 4 | 16);
    agg_kernel<false><<<AGB, 384, 0, stream>>>(AbH, el, er, off, csrc, b2, P1h, P1l, N);

    // ---- MLP head (fused lin1..lin5, 64-node blocks)
    int RBM = (N + MROWS - 1) / MROWS;
    mlp_fused<<<RBM, 256, 0, stream>>>(P1h, P1l,
                                       l1th, l1tl, l2th, l2tl, l3th, l3tl,
                                       l4th, l4tl, l5th, l5tl,
                                       lb1, lb2, lb3, lb4, lb5, out, N);
}

// Round 8
// 524.011 us; speedup vs baseline: 1.0678x; 1.0678x over previous
//
#include <hip/hip_runtime.h>
#include <hip/hip_bf16.h>

// ---------------------------------------------------------------------------
// GAT (2 GATConv + 5-layer MLP), MI355X.
// R4: bf16 hi/lo planes end-to-end, split-bf16 MFMA (3 terms), fused el/er.
// R12: prep_kernel fuses conv+convw+hist; scatter reuses cnt via atomicSub.
// R16: gemm/mlp staging -> global_load_lds(16B) + both-sides XOR swizzle.
// R17 (FAILED): both-layer fp8 gather (absmax). R18: mixed fp8/bf16 PASSED,
//     dur unchanged -> agg not bytes/line-bound. R19 (REGRESSED): 8-row
//     gather. R21 (REGRESSED): pair-loads (instr count exonerated).
// Elimination matrix closed: agg obeys dur ~= const/occupancy (Little's-law
//     miss-limited). R20 operating point (direct exp, 8-deep batch, 2 nodes/
//     block barrier-free, 384 thr) is the best found: 97+100 us. KEPT EXACTLY.
// R22: attack the ~300 us matmul bucket. All matmuls have K=128 -> 4 K-steps;
//     old loop exposed full stage latency per step (stage->drain->MFMA).
//     Now: LDS double-buffer + issue STAGE(k+1) BEFORE consuming k (T3
//     minimum 2-phase, m230). One barrier/step. gemm LDS 64KB (2 blk/CU);
//     mlp unified 16-step unrolled loop w/ cross-layer W prefetch (67KB).
//     Identical arithmetic order -> absmax unchanged.
// ---------------------------------------------------------------------------

typedef __attribute__((ext_vector_type(8))) short short8;   // 8 bf16 = 4 VGPR
typedef __attribute__((ext_vector_type(4))) float float4v;  // MFMA C/D
typedef __attribute__((ext_vector_type(2))) float floatx2;

__device__ inline short f2bf(float x) {
    union { float f; unsigned u; } v; v.f = x;
    unsigned r = v.u + 0x7FFFu + ((v.u >> 16) & 1u);   // RNE
    return (short)(r >> 16);
}
__device__ inline float bf2f(short b) {
    union { float f; unsigned u; } v;
    v.u = ((unsigned)(unsigned short)b) << 16;
    return v.f;
}
__device__ inline short8 zero8() { short8 z = {0,0,0,0,0,0,0,0}; return z; }

// ---- fp8 e4m3 pack/unpack (HW conversions on gfx950; exact SW fallback) ----
#if __has_builtin(__builtin_amdgcn_cvt_pk_fp8_f32)
__device__ inline unsigned short pk2fp8(float a, float b) {
    return (unsigned short)(__builtin_amdgcn_cvt_pk_fp8_f32(a, b, 0, false) & 0xFFFF);
}
#else
__device__ inline unsigned char f2fp8_1(float x) {
    union { float f; unsigned u; } v; v.f = x;
    unsigned s = (v.u >> 24) & 0x80u;
    unsigned au = v.u & 0x7FFFFFFFu;
    if (au >= 0x43E00000u) return (unsigned char)(s | 0x7E);   // saturate 448
    if (au < 0x3C800000u) {                                    // subnormal
        union { float f; unsigned u; } a; a.u = au;
        int k = (int)(a.f * 512.0f + 0.5f);
        if (k > 7) return (unsigned char)(s | 0x08);
        return (unsigned char)(s | (unsigned)k);
    }
    unsigned r = au + 0x0007FFFFu + ((au >> 20) & 1u);         // RNE @bit20
    unsigned e = (r >> 23) - 120u;
    unsigned m = (r >> 20) & 7u;
    if (e >= 15u && m >= 7u) { e = 15u; m = 6u; }              // avoid NaN enc
    return (unsigned char)(s | (e << 3) | m);
}
__device__ inline unsigned short pk2fp8(float a, float b) {
    return (unsigned short)f2fp8_1(a) | ((unsigned short)f2fp8_1(b) << 8);
}
#endif

#if __has_builtin(__builtin_amdgcn_cvt_pk_f32_fp8)
__device__ inline floatx2 unpk2fp8(unsigned short p) {
    return __builtin_amdgcn_cvt_pk_f32_fp8((int)p, false);
}
#else
__device__ inline float fp8_1_2f(unsigned char b) {
    unsigned s = b >> 7, e = (b >> 3) & 15u, m = b & 7u;
    float v = (e == 0) ? (float)m * 0.001953125f
                       : (float)(8u + m) * exp2f((float)((int)e - 10));
    return s ? -v : v;
}
__device__ inline floatx2 unpk2fp8(unsigned short p) {
    floatx2 r; r.x = fp8_1_2f((unsigned char)(p & 0xFF));
    r.y = fp8_1_2f((unsigned char)(p >> 8)); return r;
}
#endif

// async global->LDS, 16 B per lane (dest = wave-uniform base + lane*16)
__device__ __forceinline__ void gl_lds16(const short* g, short* l) {
    __builtin_amdgcn_global_load_lds(
        (const __attribute__((address_space(1))) void*)g,
        (__attribute__((address_space(3))) void*)l,
        16, 0, 0);
}

// XOR swizzle for 16B slots within a 64B row (8-way -> 2-way, free per m136).
#define SW(r) ((((r) >> 2) ^ (r)) & 3)

#define BM 128
#define BN 128
#define BK 32
#define MSTR 136   // act row stride in shorts (272 B = 17x16B, breaks pow2)
#define MROWS 64   // mlp_fused rows per block

// ---------------------------------------------------------------------------
// Fused prep: [0, cb) conv_split | [cb, cb+wb) weight transpose | rest hist.
__global__ void prep_kernel(
    const float* __restrict__ in_feat, short* __restrict__ P1h,
    short* __restrict__ P1l, int n4, int cb, int wb,
    const int* __restrict__ dst, int* __restrict__ cnt, int E,
    const float* __restrict__ w1, const float* __restrict__ w2,
    const float* __restrict__ m1, const float* __restrict__ m2,
    const float* __restrict__ m3, const float* __restrict__ m4,
    const float* __restrict__ w5,
    short* __restrict__ w1h, short* __restrict__ w1l,
    short* __restrict__ w2h, short* __restrict__ w2l,
    short* __restrict__ m1h, short* __restrict__ m1l,
    short* __restrict__ m2h, short* __restrict__ m2l,
    short* __restrict__ m3h, short* __restrict__ m3l,
    short* __restrict__ m4h, short* __restrict__ m4l,
    short* __restrict__ w5h, short* __restrict__ w5l)
{
    int blk = blockIdx.x;
    if (blk < cb) {
        int i = blk * 256 + threadIdx.x;
        if (i >= n4) return;
        float4 v = *(const float4*)(in_feat + (size_t)i * 4);
        float xs[4] = {v.x, v.y, v.z, v.w};
        short hs[4], ls[4];
        #pragma unroll
        for (int j = 0; j < 4; ++j) {
            hs[j] = f2bf(xs[j]);
            ls[j] = f2bf(xs[j] - bf2f(hs[j]));
        }
        *(uint2*)(P1h + (size_t)i * 4) = *(uint2*)hs;
        *(uint2*)(P1l + (size_t)i * 4) = *(uint2*)ls;
    } else if (blk < cb + wb) {
        int j = (blk - cb) * 256 + threadIdx.x;
        const float* src; short* th; short* tl; int Nc, base;
        if      (j < 49152)  { src = w1; th = w1h; tl = w1l; Nc = 384; base = 0; }
        else if (j < 98304)  { src = w2; th = w2h; tl = w2l; Nc = 384; base = 49152; }
        else if (j < 114688) { src = m1; th = m1h; tl = m1l; Nc = 128; base = 98304; }
        else if (j < 131072) { src = m2; th = m2h; tl = m2l; Nc = 128; base = 114688; }
        else if (j < 147456) { src = m3; th = m3h; tl = m3l; Nc = 128; base = 131072; }
        else if (j < 163840) { src = m4; th = m4h; tl = m4l; Nc = 128; base = 147456; }
        else if (j < 164608) { src = w5; th = w5h; tl = w5l; Nc = 6;   base = 163840; }
        else return;
        int i = j - base;
        int k = i / Nc, c = i - k * Nc;
        float v = src[i];
        short h = f2bf(v);
        th[(size_t)c * 128 + k] = h;
        tl[(size_t)c * 128 + k] = f2bf(v - bf2f(h));
    } else {
        int e = (blk - cb - wb) * 256 + threadIdx.x;
        if (e < E) atomicAdd(&cnt[dst[e]], 1);
    }
}

// ---------------------------------------------------------------------------
// GEMM (GAT layers): C[M x Nc] = A @ W, fused el/er. flags: 1 bias, 2 lrelu,
// 4 el/er, 8 fp32 C, 16 hi plane, 32 lo plane, 64 fp8 C.
// R22: LDS double-buffer; STAGE(k+1) issued before consuming k (2-phase).
__global__ __launch_bounds__(256) void gemm_mfma(
    const short* __restrict__ Ahi, const short* __restrict__ Alo,
    const short* __restrict__ Bth, const short* __restrict__ Btl,
    const float* __restrict__ bias,
    float* __restrict__ Cf, short* __restrict__ Chi, short* __restrict__ Clo,
    unsigned char* __restrict__ Cf8,
    float* __restrict__ el, float* __restrict__ er,
    const float* __restrict__ al, const float* __restrict__ ar,
    int M, int Nc, int flags)
{
    __shared__ short Ah[2][BM * BK], Al_[2][BM * BK];
    __shared__ short Bh[2][BN * BK], Bl_[2][BN * BK];

    int tid = threadIdx.x, lane = tid & 63, wave = tid >> 6;
    int l15 = lane & 15, q = lane >> 4;
    int rowBase = blockIdx.y * BM, colBase = blockIdx.x * BN;

    float4v acc[2][8];
    #pragma unroll
    for (int mt = 0; mt < 2; ++mt)
        #pragma unroll
        for (int nt = 0; nt < 8; ++nt)
            acc[mt][nt] = (float4v){0.f, 0.f, 0.f, 0.f};

    auto stage = [&](int b, int k0) {
        #pragma unroll
        for (int i = 0; i < 2; ++i) {
            int cid = tid + i * 256;             // wave-uniform base + lane
            int r = cid >> 2, sub = cid & 3;
            int gs = (sub ^ SW(r)) * 8;
            size_t ga = (size_t)(rowBase + r) * 128 + k0 + gs;
            size_t gb = (size_t)(colBase + r) * 128 + k0 + gs;
            int ld = cid * 8;
            gl_lds16(Ahi + ga, &Ah[b][ld]);
            gl_lds16(Alo + ga, &Al_[b][ld]);
            gl_lds16(Bth + gb, &Bh[b][ld]);
            gl_lds16(Btl + gb, &Bl_[b][ld]);
        }
    };

    stage(0, 0);
    __syncthreads();

    #pragma unroll
    for (int ks = 0; ks < 4; ++ks) {
        int cur = ks & 1;
        if (ks < 3) stage(cur ^ 1, (ks + 1) * BK);   // fly under MFMA below

        short8 aH[2], aL2[2];
        #pragma unroll
        for (int mt = 0; mt < 2; ++mt) {
            int row = wave * 32 + mt * 16 + l15;
            int off = row * 32 + (q ^ SW(row)) * 8;
            aH[mt]  = *(short8*)&Ah[cur][off];
            aL2[mt] = *(short8*)&Al_[cur][off];
        }
        #pragma unroll
        for (int nt = 0; nt < 8; ++nt) {
            int row = nt * 16 + l15;
            int off = row * 32 + (q ^ SW(row)) * 8;
            short8 bH = *(short8*)&Bh[cur][off];
            short8 bL = *(short8*)&Bl_[cur][off];
            #pragma unroll
            for (int mt = 0; mt < 2; ++mt) {
                acc[mt][nt] = __builtin_amdgcn_mfma_f32_16x16x32_bf16(aH[mt], bH, acc[mt][nt], 0, 0, 0);
                acc[mt][nt] = __builtin_amdgcn_mfma_f32_16x16x32_bf16(aH[mt], bL, acc[mt][nt], 0, 0, 0);
                acc[mt][nt] = __builtin_amdgcn_mfma_f32_16x16x32_bf16(aL2[mt], bH, acc[mt][nt], 0, 0, 0);
            }
        }
        __syncthreads();
    }

    if (flags & 4) {
        const float* alh = al + colBase;
        const float* arh = ar + colBase;
        float pel[2][4] = {}, per_[2][4] = {};
        #pragma unroll
        for (int nt = 0; nt < 8; ++nt) {
            float av = alh[nt * 16 + l15];
            float rv = arh[nt * 16 + l15];
            #pragma unroll
            for (int mt = 0; mt < 2; ++mt)
                #pragma unroll
                for (int i = 0; i < 4; ++i) {
                    pel[mt][i]  += acc[mt][nt][i] * av;
                    per_[mt][i] += acc[mt][nt][i] * rv;
                }
        }
        #pragma unroll
        for (int mask = 1; mask < 16; mask <<= 1)
            #pragma unroll
            for (int mt = 0; mt < 2; ++mt)
                #pragma unroll
                for (int i = 0; i < 4; ++i) {
                    pel[mt][i]  += __shfl_xor(pel[mt][i], mask);
                    per_[mt][i] += __shfl_xor(per_[mt][i], mask);
                }
        if (l15 == 0) {
            #pragma unroll
            for (int mt = 0; mt < 2; ++mt)
                #pragma unroll
                for (int i = 0; i < 4; ++i) {
                    int r = rowBase + wave * 32 + mt * 16 + q * 4 + i;
                    if (r < M) {
                        el[r * 3 + blockIdx.x] = pel[mt][i];
                        er[r * 3 + blockIdx.x] = per_[mt][i];
                    }
                }
        }
    }

    #pragma unroll
    for (int mt = 0; mt < 2; ++mt) {
        #pragma unroll
        for (int nt = 0; nt < 8; ++nt) {
            int c = colBase + nt * 16 + l15;
            bool cok = c < Nc;
            float bv = ((flags & 1) && cok) ? bias[c] : 0.f;
            #pragma unroll
            for (int i = 0; i < 4; ++i) {
                int r = rowBase + wave * 32 + mt * 16 + q * 4 + i;
                float v = acc[mt][nt][i] + bv;
                if (flags & 2) v = (v < 0.f) ? 0.01f * v : v;
                float vn = __shfl_xor(v, 1);      // neighbor (c^1), all lanes
                if (cok && r < M) {
                    size_t idx = (size_t)r * Nc + c;
                    if (flags & 8)  Cf[idx] = v;
                    if (flags & 16) {
                        short hh = f2bf(v);
                        Chi[idx] = hh;
                        if (flags & 32) Clo[idx] = f2bf(v - bf2f(hh));
                    }
                    if ((flags & 64) && !(l15 & 1))
                        *(unsigned short*)(Cf8 + idx) = pk2fp8(v, vn);
                }
            }
        }
    }
}

// ---------------------------------------------------------------------------
// Fused MLP head: 4x (128->128, bias, lrelu) + (128->6, bias) in one kernel.
// R22: unified 16-step unrolled loop; W double-buffered; stage(step+1) issued
// before consuming step (crosses layer boundaries); epilogue at step&3==3.
__global__ __launch_bounds__(256) void mlp_fused(
    const short* __restrict__ Ph, const short* __restrict__ Pl,
    const short* __restrict__ w1h, const short* __restrict__ w1l,
    const short* __restrict__ w2h, const short* __restrict__ w2l,
    const short* __restrict__ w3h, const short* __restrict__ w3l,
    const short* __restrict__ w4h, const short* __restrict__ w4l,
    const short* __restrict__ w5h, const short* __restrict__ w5l,
    const float* __restrict__ b1, const float* __restrict__ b2,
    const float* __restrict__ b3, const float* __restrict__ b4,
    const float* __restrict__ b5,
    float* __restrict__ out, int M)
{
    __shared__ short AH[MROWS * MSTR], AL[MROWS * MSTR];
    __shared__ short WH[2][128 * BK], WL[2][128 * BK];

    int tid = threadIdx.x, lane = tid & 63, wave = tid >> 6;
    int l15 = lane & 15, q = lane >> 4;
    int rowBase = blockIdx.x * MROWS;

    #pragma unroll
    for (int s = 0; s < 4; ++s) {
        int idx = tid + s * 256;
        int r = idx >> 4, kq = (idx & 15) * 8;
        int gr = rowBase + r;
        short8 vh = zero8(), vl = zero8();
        if (gr < M) {
            vh = *(const short8*)(Ph + (size_t)gr * 128 + kq);
            vl = *(const short8*)(Pl + (size_t)gr * 128 + kq);
        }
        *(short8*)&AH[r * MSTR + kq] = vh;
        *(short8*)&AL[r * MSTR + kq] = vl;
    }

    const short* Whs[4] = {w1h, w2h, w3h, w4h};
    const short* Wls[4] = {w1l, w2l, w3l, w4l};
    const float* Bss[4] = {b1, b2, b3, b4};

    auto stageW = [&](int b, const short* wh, const short* wl, int k0) {
        #pragma unroll
        for (int i = 0; i < 4; ++i) {          // i<2: hi plane, i>=2: lo
            int c2 = tid + (i & 1) * 256;       // 0..511
            int r = c2 >> 2, sub = c2 & 3;
            int gs = (sub ^ SW(r)) * 8;
            if (i < 2) gl_lds16(wh + (size_t)r * 128 + k0 + gs, &WH[b][c2 * 8]);
            else       gl_lds16(wl + (size_t)r * 128 + k0 + gs, &WL[b][c2 * 8]);
        }
    };

    float4v acc[8];
    #pragma unroll
    for (int nt = 0; nt < 8; ++nt)
        acc[nt] = (float4v){0.f, 0.f, 0.f, 0.f};

    stageW(0, Whs[0], Wls[0], 0);
    __syncthreads();

    #pragma unroll
    for (int step = 0; step < 16; ++step) {
        int L = step >> 2, k0 = (step & 3) * BK;
        int cur = step & 1;
        if (step < 15) {
            int ns = step + 1;
            stageW(cur ^ 1, Whs[ns >> 2], Wls[ns >> 2], (ns & 3) * BK);
        }
        int offa = (wave * 16 + l15) * MSTR + k0 + q * 8;
        short8 aH  = *(short8*)&AH[offa];
        short8 aL2 = *(short8*)&AL[offa];
        #pragma unroll
        for (int nt = 0; nt < 8; ++nt) {
            int row = nt * 16 + l15;
            int off = row * 32 + (q ^ SW(row)) * 8;
            short8 bH = *(short8*)&WH[cur][off];
            short8 bL = *(short8*)&WL[cur][off];
            acc[nt] = __builtin_amdgcn_mfma_f32_16x16x32_bf16(aH, bH, acc[nt], 0, 0, 0);
            acc[nt] = __builtin_amdgcn_mfma_f32_16x16x32_bf16(aH, bL, acc[nt], 0, 0, 0);
            acc[nt] = __builtin_amdgcn_mfma_f32_16x16x32_bf16(aL2, bH, acc[nt], 0, 0, 0);
        }
        if ((step & 3) == 3) {
            __syncthreads();                   // all AH/AL reads of layer done
            #pragma unroll
            for (int nt = 0; nt < 8; ++nt) {
                int c = nt * 16 + l15;
                float bv = Bss[L][c];
                #pragma unroll
                for (int i = 0; i < 4; ++i) {
                    int r = wave * 16 + q * 4 + i;
                    float v = acc[nt][i] + bv;
                    v = (v < 0.f) ? 0.01f * v : v;
                    short hh = f2bf(v);
                    AH[r * MSTR + c] = hh;
                    AL[r * MSTR + c] = f2bf(v - bf2f(hh));
                }
                acc[nt] = (float4v){0.f, 0.f, 0.f, 0.f};
            }
        }
        __syncthreads();
    }

    float4v acc5 = (float4v){0.f, 0.f, 0.f, 0.f};
    for (int k0 = 0; k0 < 128; k0 += BK) {
        if (tid < 128) {
            int plane = tid >> 6, rem = tid & 63;
            int c = rem >> 2, sub = rem & 3;
            short8 v = zero8();
            if (c < 6)
                v = *(const short8*)((plane ? w5l : w5h) + (size_t)c * 128 + k0 + sub * 8);
            *(short8*)&((plane ? WL[0] : WH[0])[c * 32 + (sub ^ SW(c)) * 8]) = v;
        }
        __syncthreads();
        int offa = (wave * 16 + l15) * MSTR + k0 + q * 8;
        short8 aH  = *(short8*)&AH[offa];
        short8 aL2 = *(short8*)&AL[offa];
        int offb = l15 * 32 + (q ^ SW(l15)) * 8;
        short8 bH = *(short8*)&WH[0][offb];
        short8 bL = *(short8*)&WL[0][offb];
        acc5 = __builtin_amdgcn_mfma_f32_16x16x32_bf16(aH, bH, acc5, 0, 0, 0);
        acc5 = __builtin_amdgcn_mfma_f32_16x16x32_bf16(aH, bL, acc5, 0, 0, 0);
        acc5 = __builtin_amdgcn_mfma_f32_16x16x32_bf16(aL2, bH, acc5, 0, 0, 0);
        __syncthreads();
    }
    if (l15 < 6) {
        float bv = b5[l15];
        #pragma unroll
        for (int i = 0; i < 4; ++i) {
            int r = rowBase + wave * 16 + q * 4 + i;
            if (r < M) out[(size_t)r * 6 + l15] = acc5[i] + bv;
        }
    }
}

// ---------------------------------------------------------------------------
// CSR build (hist lives in prep_kernel)
__global__ __launch_bounds__(1024) void scan_block(const int* __restrict__ cnt,
                                                   int* __restrict__ off,
                                                   int* __restrict__ bsum, int n)
{
    __shared__ int tmp[1024];
    int tid = threadIdx.x;
    int i = blockIdx.x * 1024 + tid;
    int v = (i < n) ? cnt[i] : 0;
    tmp[tid] = v;
    __syncthreads();
    for (int s = 1; s < 1024; s <<= 1) {
        int t = (tid >= s) ? tmp[tid - s] : 0;
        __syncthreads();
        tmp[tid] += t;
        __syncthreads();
    }
    if (i < n) off[i] = tmp[tid] - v;
    if (tid == 1023) bsum[blockIdx.x] = tmp[1023];
}

__global__ void scan_add2(int* __restrict__ off, const int* __restrict__ bsum,
                          int n, int nb)
{
    __shared__ int pre[64];
    int tid = threadIdx.x;
    if (tid < 64) {
        int v = (tid < nb) ? bsum[tid] : 0;
        #pragma unroll
        for (int s = 1; s < 64; s <<= 1) {
            int t = __shfl_up(v, s);
            if (tid >= s) v += t;
        }
        pre[tid] = v;
    }
    __syncthreads();
    int i = blockIdx.x * blockDim.x + tid;
    if (i < n) {
        int chunk = i >> 10;
        off[i] += chunk ? pre[chunk - 1] : 0;
    }
    if (i == 0) off[n] = pre[nb - 1];
}

__global__ void scatter_kernel(const int* __restrict__ src, const int* __restrict__ dst,
                               const int* __restrict__ off, int* __restrict__ cnt,
                               int* __restrict__ csrc, int E)
{
    int e = blockIdx.x * blockDim.x + threadIdx.x;
    if (e < E) {
        int d = dst[e];
        int p = atomicSub(&cnt[d], 1) - 1;
        csrc[off[d] + p] = src[e];
    }
}

// ---------------------------------------------------------------------------
// Fused edge-softmax + weighted gather + bias + lrelu + head-mean.
// R20 (proven best): 2 nodes per block, 384 threads = 6 waves; wave u =
// (node nl, head). Lane l owns feature pair (2l, 2l+1). Direct exp, per-lane
// den + single final tree, 8-deep gather load batching, barrier-free chunk
// loop (per-wave LDS staging), one final __syncthreads for head-mean.
template <bool FP8>
__global__ __launch_bounds__(384) void agg_kernel(
    const void* __restrict__ hsrc, const float* __restrict__ el,
    const float* __restrict__ er, const int* __restrict__ off,
    const int* __restrict__ csrc, const float* __restrict__ bias,
    short* __restrict__ outH, short* __restrict__ outL, int N)
{
    constexpr int ROWB = FP8 ? 384 : 768;   // full row bytes
    constexpr int SEGB = ROWB / 3;          // per-head segment bytes

    const unsigned char* hb = (const unsigned char*)hsrc;
    int tid = threadIdx.x;         // 0..383
    int u = tid >> 6;              // wave 0..5
    int nl = u / 3;                // node-local 0/1
    int head = u - nl * 3;         // 0..2
    int l = tid & 63;
    int n = blockIdx.x * 2 + nl;
    bool active = (n < N);

    __shared__ int   ssrcS[6][64];
    __shared__ float swS[6][64];
    __shared__ float smS[2][384];

    int beg = 0, deg = 0;
    float erv = 0.f;
    if (active) {
        beg = off[n];
        deg = off[n + 1] - beg;
        erv = er[n * 3 + head];
    }

    const unsigned char* hseg = hb + head * SEGB + l * (FP8 ? 2 : 4);
    float ax = 0.f, ay = 0.f, denl = 0.f;

    for (int base = 0; base < deg; base += 64) {
        int cnt = min(64, deg - base);
        int s_l = 0; float w = 0.f;
        if (l < cnt) {
            s_l = csrc[beg + base + l];
            float t = el[s_l * 3 + head] + erv;
            t = (t < 0.f) ? 0.2f * t : t;
            w = __expf(t);                 // direct exp: logits bounded
        }
        denl += w;
        ssrcS[u][l] = s_l;                 // per-wave region: no barrier
        swS[u][l]   = w;                   // (same-wave lgkmcnt ordering)
        for (int q0 = 0; q0 < cnt; q0 += 8) {
            int sA[8]; float wA[8]; unsigned vA[8];
            #pragma unroll
            for (int b = 0; b < 8; ++b) {
                int e = q0 + b;            // <= 63 always; pads have w=0,s=0
                sA[b] = ssrcS[u][e];
                wA[b] = swS[u][e];
            }
            #pragma unroll
            for (int b = 0; b < 8; ++b) {
                if constexpr (FP8)
                    vA[b] = *(const unsigned short*)(hseg + (size_t)sA[b] * ROWB);
                else
                    vA[b] = *(const unsigned*)(hseg + (size_t)sA[b] * ROWB);
            }
            #pragma unroll
            for (int b = 0; b < 8; ++b) {
                if constexpr (FP8) {
                    floatx2 f = unpk2fp8((unsigned short)vA[b]);
                    ax += wA[b] * f.x;
                    ay += wA[b] * f.y;
                } else {
                    union { unsigned u; float f; } f0, f1;
                    f0.u = vA[b] << 16; f1.u = vA[b] & 0xffff0000u;
                    ax += wA[b] * f0.f;
                    ay += wA[b] * f1.f;
                }
            }
        }
    }

    float den = denl;
    #pragma unroll
    for (int msk = 1; msk < 64; msk <<= 1) den += __shfl_xor(den, msk);
    float r = 1.f / (den + 1e-9f);
    if (deg == 0) r = 0.f;

    if (active) {
        int fb = head * 128 + 2 * l;
        float2 bv = *(const float2*)(bias + fb);
        float vx = ax * r + bv.x; vx = (vx < 0.f) ? 0.01f * vx : vx;
        float vy = ay * r + bv.y; vy = (vy < 0.f) ? 0.01f * vy : vy;
        smS[nl][fb]     = vx;
        smS[nl][fb + 1] = vy;
    }
    __syncthreads();
    if (tid < 128) {
        int mn = tid >> 6;                 // node-local 0/1
        int n2 = blockIdx.x * 2 + mn;
        if (n2 < N) {
            int f0i = (tid & 63) * 2, f1i = f0i + 1;
            float mx = (smS[mn][f0i] + smS[mn][128 + f0i] + smS[mn][256 + f0i]) * (1.0f / 3.0f);
            float my = (smS[mn][f1i] + smS[mn][128 + f1i] + smS[mn][256 + f1i]) * (1.0f / 3.0f);
            short hx = f2bf(mx), lx = f2bf(mx - bf2f(hx));
            short hy = f2bf(my), ly = f2bf(my - bf2f(hy));
            unsigned ph = (unsigned)(unsigned short)hx | ((unsigned)(unsigned short)hy << 16);
            unsigned pl = (unsigned)(unsigned short)lx | ((unsigned)(unsigned short)ly << 16);
            *(unsigned*)(outH + (size_t)n2 * 128 + f0i) = ph;
            *(unsigned*)(outL + (size_t)n2 * 128 + f0i) = pl;
        }
    }
}

// ---------------------------------------------------------------------------
extern "C" void kernel_launch(void* const* d_in, const int* in_sizes, int n_in,
                              void* d_out, int out_size, void* d_ws, size_t ws_size,
                              hipStream_t stream)
{
    const float* in_feat = (const float*)d_in[0];
    const int*   src     = (const int*)d_in[1];
    const int*   dst     = (const int*)d_in[2];
    const float* W1  = (const float*)d_in[3];
    const float* al1 = (const float*)d_in[4];
    const float* ar1 = (const float*)d_in[5];
    const float* b1  = (const float*)d_in[6];
    const float* W2  = (const float*)d_in[7];
    const float* al2 = (const float*)d_in[8];
    const float* ar2 = (const float*)d_in[9];
    const float* b2  = (const float*)d_in[10];
    const float* lw1 = (const float*)d_in[11];
    const float* lb1 = (const float*)d_in[12];
    const float* lw2 = (const float*)d_in[13];
    const float* lb2 = (const float*)d_in[14];
    const float* lw3 = (const float*)d_in[15];
    const float* lb3 = (const float*)d_in[16];
    const float* lw4 = (const float*)d_in[17];
    const float* lb4 = (const float*)d_in[18];
    const float* lw5 = (const float*)d_in[19];
    const float* lb5 = (const float*)d_in[20];

    const int N = in_sizes[0] / 128;   // 50000
    const int E = in_sizes[1];         // 800000

    size_t o = 0;
    auto alloc = [&](size_t bytes) { size_t p = o; o = (o + bytes + 255) & ~(size_t)255; return p; };
    char* ws = (char*)d_ws;
    short* P1h = (short*)(ws + alloc((size_t)N * 128 * 2));
    short* P1l = (short*)(ws + alloc((size_t)N * 128 * 2));
    short* P2h = (short*)(ws + alloc((size_t)N * 128 * 2));
    short* P2l = (short*)(ws + alloc((size_t)N * 128 * 2));
    short* AbH = (short*)(ws + alloc((size_t)N * 384 * 2));          // bf16 gemm out (L2)
    unsigned char* Af8 = (unsigned char*)(ws + alloc((size_t)N * 384)); // fp8 gemm out (L1)
    float* el  = (float*)(ws + alloc((size_t)N * 3 * 4));
    float* er  = (float*)(ws + alloc((size_t)N * 3 * 4));
    int*   cnt  = (int*)(ws + alloc((size_t)N * 4));
    int*   off  = (int*)(ws + alloc((size_t)(N + 1) * 4));
    int*   bsum = (int*)(ws + alloc((size_t)4096));
    int*   csrc = (int*)(ws + alloc((size_t)E * 4));
    short* w1th = (short*)(ws + alloc((size_t)384 * 128 * 2));
    short* w1tl = (short*)(ws + alloc((size_t)384 * 128 * 2));
    short* w2th = (short*)(ws + alloc((size_t)384 * 128 * 2));
    short* w2tl = (short*)(ws + alloc((size_t)384 * 128 * 2));
    short* l1th = (short*)(ws + alloc((size_t)128 * 128 * 2));
    short* l1tl = (short*)(ws + alloc((size_t)128 * 128 * 2));
    short* l2th = (short*)(ws + alloc((size_t)128 * 128 * 2));
    short* l2tl = (short*)(ws + alloc((size_t)128 * 128 * 2));
    short* l3th = (short*)(ws + alloc((size_t)128 * 128 * 2));
    short* l3tl = (short*)(ws + alloc((size_t)128 * 128 * 2));
    short* l4th = (short*)(ws + alloc((size_t)128 * 128 * 2));
    short* l4tl = (short*)(ws + alloc((size_t)128 * 128 * 2));
    short* l5th = (short*)(ws + alloc((size_t)6 * 128 * 2));
    short* l5tl = (short*)(ws + alloc((size_t)6 * 128 * 2));
    (void)ws_size;

    float* out = (float*)d_out;

    // ---- fused prep: conv_split + weight transpose + hist (one launch)
    hipMemsetAsync(cnt, 0, (size_t)N * 4, stream);
    int n4 = N * 128 / 4;
    int cb = (n4 + 255) / 256;
    int wb = (164608 + 255) / 256;
    int hb = (E + 255) / 256;
    prep_kernel<<<cb + wb + hb, 256, 0, stream>>>(
        in_feat, P1h, P1l, n4, cb, wb, dst, cnt, E,
        W1, W2, lw1, lw2, lw3, lw4, lw5,
        w1th, w1tl, w2th, w2tl, l1th, l1tl, l2th, l2tl,
        l3th, l3tl, l4th, l4tl, l5th, l5tl);

    // ---- CSR scan + scatter
    int nb = (N + 1023) / 1024;
    scan_block<<<nb, 1024, 0, stream>>>(cnt, off, bsum, N);
    scan_add2<<<(N + 255) / 256, 256, 0, stream>>>(off, bsum, N, nb);
    scatter_kernel<<<(E + 255) / 256, 256, 0, stream>>>(src, dst, off, cnt, csrc, E);

    int RB = (N + BM - 1) / BM;
    auto gemm = [&](const short* ah, const short* alo, const short* bth, const short* btl,
                    const float* bias, float* cf, short* chi, short* clo,
                    unsigned char* cf8,
                    float* elp, float* erp, const float* alp, const float* arp,
                    int Nc, int flags) {
        dim3 grid((Nc + BN - 1) / BN, RB);
        gemm_mfma<<<grid, 256, 0, stream>>>(ah, alo, bth, btl, bias, cf, chi, clo, cf8,
                                            elp, erp, alp, arp, N, Nc, flags);
    };

    int AGB = (N + 1) / 2;
    // ---- GAT layer 1 (fp8 h for gather — error attenuated by downstream net)
    gemm(P1h, P1l, w1th, w1tl, nullptr, nullptr, nullptr, nullptr, Af8, el, er, al1, ar1, 384, 4 | 64);
    agg_kernel<true><<<AGB, 384, 0, stream>>>(Af8, el, er, off, csrc, b1, P2h, P2l, N);

    // ---- GAT layer 2 (bf16 h for gather — precision-critical)
    gemm(P2h, P2l, w2th, w2tl, nullptr, nullptr, AbH, nullptr, nullptr, el, er, al2, ar2, 384, 4 | 16);
    agg_kernel<false><<<AGB, 384, 0, stream>>>(AbH, el, er, off, csrc, b2, P1h, P1l, N);

    // ---- MLP head (fused lin1..lin5, 64-node blocks)
    int RBM = (N + MROWS - 1) / MROWS;
    mlp_fused<<<RBM, 256, 0, stream>>>(P1h, P1l,
                                       l1th, l1tl, l2th, l2tl, l3th, l3tl,
                                       l4th, l4tl, l5th, l5tl,
                                       lb1, lb2, lb3, lb4, lb5, out, N);
}

// Round 9
// 495.656 us; speedup vs baseline: 1.1289x; 1.0572x over previous
//
#include <hip/hip_runtime.h>
#include <hip/hip_bf16.h>

// ---------------------------------------------------------------------------
// GAT (2 GATConv + 5-layer MLP), MI355X.
// R4: bf16 hi/lo planes end-to-end, split-bf16 MFMA (3 terms), fused el/er.
// R12: prep_kernel fuses conv+convw+hist; scatter reuses cnt via atomicSub.
// R16: gemm/mlp staging -> global_load_lds(16B) + both-sides XOR swizzle.
// R17 (FAILED): both-layer fp8-e4m3 gather, absmax 1.86e-5 (3-bit mantissa).
// R18-R21: elimination matrix on the OLD 192-thr agg: latency-floored.
// R20 (520.7 us, proven): agg 2 nodes/block 384-thr, direct exp, 8-deep
//     batching, barrier-free chunk loop. agg2 now delivers 3.05 TB/s ==
//     random-line HBM ceiling -> bytes-bound again in THIS structure.
// R22 (neutral): 2-phase matmul dbuf; reverted (K=128 too short to cover
//     drain; LDS doubling costs occupancy).
// R23: INT8 ROWMAX-SCALED gather, BOTH layers (1 B/elem, same geometry as
//     fp8 but ~3x lower quant error: scale=rowmax/127 per (row,head)).
//     Encode in gemm epilogue (nt-loop + 4-step shfl rowmax reduce); scale
//     folded into edge weight via combined ELS[{el,scale}] array (el+scale
//     in ONE 8B load). den uses unscaled w. gemm no longer writes bf16 AbH
//     (-38.4 MB). Calibrated error model predicts absmax ~1e-5 < 1.495e-5.
// ---------------------------------------------------------------------------

typedef __attribute__((ext_vector_type(8))) short short8;   // 8 bf16 = 4 VGPR
typedef __attribute__((ext_vector_type(4))) float float4v;  // MFMA C/D

__device__ inline short f2bf(float x) {
    union { float f; unsigned u; } v; v.f = x;
    unsigned r = v.u + 0x7FFFu + ((v.u >> 16) & 1u);   // RNE
    return (short)(r >> 16);
}
__device__ inline float bf2f(short b) {
    union { float f; unsigned u; } v;
    v.u = ((unsigned)(unsigned short)b) << 16;
    return v.f;
}
__device__ inline short8 zero8() { short8 z = {0,0,0,0,0,0,0,0}; return z; }

// async global->LDS, 16 B per lane (dest = wave-uniform base + lane*16)
__device__ __forceinline__ void gl_lds16(const short* g, short* l) {
    __builtin_amdgcn_global_load_lds(
        (const __attribute__((address_space(1))) void*)g,
        (__attribute__((address_space(3))) void*)l,
        16, 0, 0);
}

// XOR swizzle for 16B slots within a 64B row (8-way -> 2-way, free per m136).
#define SW(r) ((((r) >> 2) ^ (r)) & 3)

#define BM 128
#define BN 128
#define BK 32
#define MSTR 136   // act row stride in shorts (272 B = 17x16B, breaks pow2)
#define MROWS 64   // mlp_fused rows per block

// ---------------------------------------------------------------------------
// Fused prep: [0, cb) conv_split | [cb, cb+wb) weight transpose | rest hist.
__global__ void prep_kernel(
    const float* __restrict__ in_feat, short* __restrict__ P1h,
    short* __restrict__ P1l, int n4, int cb, int wb,
    const int* __restrict__ dst, int* __restrict__ cnt, int E,
    const float* __restrict__ w1, const float* __restrict__ w2,
    const float* __restrict__ m1, const float* __restrict__ m2,
    const float* __restrict__ m3, const float* __restrict__ m4,
    const float* __restrict__ w5,
    short* __restrict__ w1h, short* __restrict__ w1l,
    short* __restrict__ w2h, short* __restrict__ w2l,
    short* __restrict__ m1h, short* __restrict__ m1l,
    short* __restrict__ m2h, short* __restrict__ m2l,
    short* __restrict__ m3h, short* __restrict__ m3l,
    short* __restrict__ m4h, short* __restrict__ m4l,
    short* __restrict__ w5h, short* __restrict__ w5l)
{
    int blk = blockIdx.x;
    if (blk < cb) {
        int i = blk * 256 + threadIdx.x;
        if (i >= n4) return;
        float4 v = *(const float4*)(in_feat + (size_t)i * 4);
        float xs[4] = {v.x, v.y, v.z, v.w};
        short hs[4], ls[4];
        #pragma unroll
        for (int j = 0; j < 4; ++j) {
            hs[j] = f2bf(xs[j]);
            ls[j] = f2bf(xs[j] - bf2f(hs[j]));
        }
        *(uint2*)(P1h + (size_t)i * 4) = *(uint2*)hs;
        *(uint2*)(P1l + (size_t)i * 4) = *(uint2*)ls;
    } else if (blk < cb + wb) {
        int j = (blk - cb) * 256 + threadIdx.x;
        const float* src; short* th; short* tl; int Nc, base;
        if      (j < 49152)  { src = w1; th = w1h; tl = w1l; Nc = 384; base = 0; }
        else if (j < 98304)  { src = w2; th = w2h; tl = w2l; Nc = 384; base = 49152; }
        else if (j < 114688) { src = m1; th = m1h; tl = m1l; Nc = 128; base = 98304; }
        else if (j < 131072) { src = m2; th = m2h; tl = m2l; Nc = 128; base = 114688; }
        else if (j < 147456) { src = m3; th = m3h; tl = m3l; Nc = 128; base = 131072; }
        else if (j < 163840) { src = m4; th = m4h; tl = m4l; Nc = 128; base = 147456; }
        else if (j < 164608) { src = w5; th = w5h; tl = w5l; Nc = 6;   base = 163840; }
        else return;
        int i = j - base;
        int k = i / Nc, c = i - k * Nc;
        float v = src[i];
        short h = f2bf(v);
        th[(size_t)c * 128 + k] = h;
        tl[(size_t)c * 128 + k] = f2bf(v - bf2f(h));
    } else {
        int e = (blk - cb - wb) * 256 + threadIdx.x;
        if (e < E) atomicAdd(&cnt[dst[e]], 1);
    }
}

// ---------------------------------------------------------------------------
// GEMM (GAT layers): h = A @ W for one head per col-block (Nc=384, BN=128 ->
// blockIdx.x == head). Outputs: int8 rowmax-quantized C (Cq), combined
// ELS[{el,scale}] (8B per (row,head)), er. All from exact fp32 acc.
__global__ __launch_bounds__(256) void gemm_mfma(
    const short* __restrict__ Ahi, const short* __restrict__ Alo,
    const short* __restrict__ Bth, const short* __restrict__ Btl,
    unsigned char* __restrict__ Cq,
    float* __restrict__ els, float* __restrict__ er,
    const float* __restrict__ al, const float* __restrict__ ar,
    int M, int Nc)
{
    __shared__ short Ah[BM * BK], Al_[BM * BK];
    __shared__ short Bh[BN * BK], Bl_[BN * BK];

    int tid = threadIdx.x, lane = tid & 63, wave = tid >> 6;
    int l15 = lane & 15, q = lane >> 4;
    int rowBase = blockIdx.y * BM, colBase = blockIdx.x * BN;

    float4v acc[2][8];
    #pragma unroll
    for (int mt = 0; mt < 2; ++mt)
        #pragma unroll
        for (int nt = 0; nt < 8; ++nt)
            acc[mt][nt] = (float4v){0.f, 0.f, 0.f, 0.f};

    for (int k0 = 0; k0 < 128; k0 += BK) {
        #pragma unroll
        for (int i = 0; i < 2; ++i) {
            int cid = tid + i * 256;             // wave-uniform base + lane
            int r = cid >> 2, sub = cid & 3;
            int gs = (sub ^ SW(r)) * 8;
            size_t ga = (size_t)(rowBase + r) * 128 + k0 + gs;
            size_t gb = (size_t)(colBase + r) * 128 + k0 + gs;
            int ld = cid * 8;
            gl_lds16(Ahi + ga, Ah  + ld);
            gl_lds16(Alo + ga, Al_ + ld);
            gl_lds16(Bth + gb, Bh  + ld);
            gl_lds16(Btl + gb, Bl_ + ld);
        }
        __syncthreads();

        short8 aH[2], aL2[2];
        #pragma unroll
        for (int mt = 0; mt < 2; ++mt) {
            int row = wave * 32 + mt * 16 + l15;
            int off = row * 32 + (q ^ SW(row)) * 8;
            aH[mt]  = *(short8*)&Ah[off];
            aL2[mt] = *(short8*)&Al_[off];
        }
        #pragma unroll
        for (int nt = 0; nt < 8; ++nt) {
            int row = nt * 16 + l15;
            int off = row * 32 + (q ^ SW(row)) * 8;
            short8 bH = *(short8*)&Bh[off];
            short8 bL = *(short8*)&Bl_[off];
            #pragma unroll
            for (int mt = 0; mt < 2; ++mt) {
                acc[mt][nt] = __builtin_amdgcn_mfma_f32_16x16x32_bf16(aH[mt], bH, acc[mt][nt], 0, 0, 0);
                acc[mt][nt] = __builtin_amdgcn_mfma_f32_16x16x32_bf16(aH[mt], bL, acc[mt][nt], 0, 0, 0);
                acc[mt][nt] = __builtin_amdgcn_mfma_f32_16x16x32_bf16(aL2[mt], bH, acc[mt][nt], 0, 0, 0);
            }
        }
        __syncthreads();
    }

    // ---- el/er from exact fp32 acc
    {
        const float* alh = al + colBase;
        const float* arh = ar + colBase;
        float pel[2][4] = {}, per_[2][4] = {};
        #pragma unroll
        for (int nt = 0; nt < 8; ++nt) {
            float av = alh[nt * 16 + l15];
            float rv = arh[nt * 16 + l15];
            #pragma unroll
            for (int mt = 0; mt < 2; ++mt)
                #pragma unroll
                for (int i = 0; i < 4; ++i) {
                    pel[mt][i]  += acc[mt][nt][i] * av;
                    per_[mt][i] += acc[mt][nt][i] * rv;
                }
        }
        #pragma unroll
        for (int mask = 1; mask < 16; mask <<= 1)
            #pragma unroll
            for (int mt = 0; mt < 2; ++mt)
                #pragma unroll
                for (int i = 0; i < 4; ++i) {
                    pel[mt][i]  += __shfl_xor(pel[mt][i], mask);
                    per_[mt][i] += __shfl_xor(per_[mt][i], mask);
                }
        if (l15 == 0) {
            #pragma unroll
            for (int mt = 0; mt < 2; ++mt)
                #pragma unroll
                for (int i = 0; i < 4; ++i) {
                    int r = rowBase + wave * 32 + mt * 16 + q * 4 + i;
                    if (r < M) {
                        els[(size_t)(r * 3 + blockIdx.x) * 2] = pel[mt][i];
                        er[r * 3 + blockIdx.x] = per_[mt][i];
                    }
                }
        }
    }

    // ---- int8 rowmax quantization: scale = rowmax/127 per (row, head)
    #pragma unroll
    for (int mt = 0; mt < 2; ++mt) {
        #pragma unroll
        for (int i = 0; i < 4; ++i) {
            float rm = 0.f;
            #pragma unroll
            for (int nt = 0; nt < 8; ++nt)
                rm = fmaxf(rm, fabsf(acc[mt][nt][i]));
            #pragma unroll
            for (int mask = 1; mask < 16; mask <<= 1)
                rm = fmaxf(rm, __shfl_xor(rm, mask));
            int r = rowBase + wave * 32 + mt * 16 + q * 4 + i;
            float inv = 127.f / fmaxf(rm, 1e-30f);
            if (l15 == 0 && r < M)
                els[(size_t)(r * 3 + blockIdx.x) * 2 + 1] = rm * (1.f / 127.f);
            #pragma unroll
            for (int nt = 0; nt < 8; ++nt) {
                int c = colBase + nt * 16 + l15;
                int qi = (int)rintf(acc[mt][nt][i] * inv);
                int qn = __shfl_xor(qi, 1);        // neighbor col c^1
                if (!(l15 & 1) && r < M && c < Nc) {
                    unsigned short pk = (unsigned short)((qi & 0xFF) | ((qn & 0xFF) << 8));
                    *(unsigned short*)(Cq + (size_t)r * Nc + c) = pk;
                }
            }
        }
    }
}

// ---------------------------------------------------------------------------
// Fused MLP head: 4x (128->128, bias, lrelu) + (128->6, bias) in one kernel.
// (R20/R16 proven form.)
__global__ __launch_bounds__(256) void mlp_fused(
    const short* __restrict__ Ph, const short* __restrict__ Pl,
    const short* __restrict__ w1h, const short* __restrict__ w1l,
    const short* __restrict__ w2h, const short* __restrict__ w2l,
    const short* __restrict__ w3h, const short* __restrict__ w3l,
    const short* __restrict__ w4h, const short* __restrict__ w4l,
    const short* __restrict__ w5h, const short* __restrict__ w5l,
    const float* __restrict__ b1, const float* __restrict__ b2,
    const float* __restrict__ b3, const float* __restrict__ b4,
    const float* __restrict__ b5,
    float* __restrict__ out, int M)
{
    __shared__ short AH[MROWS * MSTR], AL[MROWS * MSTR];
    __shared__ short WH[128 * BK], WL[128 * BK];

    int tid = threadIdx.x, lane = tid & 63, wave = tid >> 6;
    int l15 = lane & 15, q = lane >> 4;
    int rowBase = blockIdx.x * MROWS;

    #pragma unroll
    for (int s = 0; s < 4; ++s) {
        int idx = tid + s * 256;
        int r = idx >> 4, kq = (idx & 15) * 8;
        int gr = rowBase + r;
        short8 vh = zero8(), vl = zero8();
        if (gr < M) {
            vh = *(const short8*)(Ph + (size_t)gr * 128 + kq);
            vl = *(const short8*)(Pl + (size_t)gr * 128 + kq);
        }
        *(short8*)&AH[r * MSTR + kq] = vh;
        *(short8*)&AL[r * MSTR + kq] = vl;
    }

    const short* Whs[4] = {w1h, w2h, w3h, w4h};
    const short* Wls[4] = {w1l, w2l, w3l, w4l};
    const float* Bss[4] = {b1, b2, b3, b4};

    #pragma unroll
    for (int L = 0; L < 4; ++L) {
        float4v acc[8];
        #pragma unroll
        for (int nt = 0; nt < 8; ++nt)
            acc[nt] = (float4v){0.f, 0.f, 0.f, 0.f};

        for (int k0 = 0; k0 < 128; k0 += BK) {
            #pragma unroll
            for (int i = 0; i < 4; ++i) {          // i<2: hi plane, i>=2: lo
                int c2 = tid + (i & 1) * 256;       // 0..511
                int r = c2 >> 2, sub = c2 & 3;
                int gs = (sub ^ SW(r)) * 8;
                if (i < 2) gl_lds16(Whs[L] + (size_t)r * 128 + k0 + gs, WH + c2 * 8);
                else       gl_lds16(Wls[L] + (size_t)r * 128 + k0 + gs, WL + c2 * 8);
            }
            __syncthreads();
            int offa = (wave * 16 + l15) * MSTR + k0 + q * 8;
            short8 aH  = *(short8*)&AH[offa];
            short8 aL2 = *(short8*)&AL[offa];
            #pragma unroll
            for (int nt = 0; nt < 8; ++nt) {
                int row = nt * 16 + l15;
                int off = row * 32 + (q ^ SW(row)) * 8;
                short8 bH = *(short8*)&WH[off];
                short8 bL = *(short8*)&WL[off];
                acc[nt] = __builtin_amdgcn_mfma_f32_16x16x32_bf16(aH, bH, acc[nt], 0, 0, 0);
                acc[nt] = __builtin_amdgcn_mfma_f32_16x16x32_bf16(aH, bL, acc[nt], 0, 0, 0);
                acc[nt] = __builtin_amdgcn_mfma_f32_16x16x32_bf16(aL2, bH, acc[nt], 0, 0, 0);
            }
            __syncthreads();
        }
        #pragma unroll
        for (int nt = 0; nt < 8; ++nt) {
            int c = nt * 16 + l15;
            float bv = Bss[L][c];
            #pragma unroll
            for (int i = 0; i < 4; ++i) {
                int r = wave * 16 + q * 4 + i;
                float v = acc[nt][i] + bv;
                v = (v < 0.f) ? 0.01f * v : v;
                short hh = f2bf(v);
                AH[r * MSTR + c] = hh;
                AL[r * MSTR + c] = f2bf(v - bf2f(hh));
            }
        }
        __syncthreads();
    }

    float4v acc5 = (float4v){0.f, 0.f, 0.f, 0.f};
    for (int k0 = 0; k0 < 128; k0 += BK) {
        if (tid < 128) {
            int plane = tid >> 6, rem = tid & 63;
            int c = rem >> 2, sub = rem & 3;
            short8 v = zero8();
            if (c < 6)
                v = *(const short8*)((plane ? w5l : w5h) + (size_t)c * 128 + k0 + sub * 8);
            *(short8*)&((plane ? WL : WH)[c * 32 + (sub ^ SW(c)) * 8]) = v;
        }
        __syncthreads();
        int offa = (wave * 16 + l15) * MSTR + k0 + q * 8;
        short8 aH  = *(short8*)&AH[offa];
        short8 aL2 = *(short8*)&AL[offa];
        int offb = l15 * 32 + (q ^ SW(l15)) * 8;
        short8 bH = *(short8*)&WH[offb];
        short8 bL = *(short8*)&WL[offb];
        acc5 = __builtin_amdgcn_mfma_f32_16x16x32_bf16(aH, bH, acc5, 0, 0, 0);
        acc5 = __builtin_amdgcn_mfma_f32_16x16x32_bf16(aH, bL, acc5, 0, 0, 0);
        acc5 = __builtin_amdgcn_mfma_f32_16x16x32_bf16(aL2, bH, acc5, 0, 0, 0);
        __syncthreads();
    }
    if (l15 < 6) {
        float bv = b5[l15];
        #pragma unroll
        for (int i = 0; i < 4; ++i) {
            int r = rowBase + wave * 16 + q * 4 + i;
            if (r < M) out[(size_t)r * 6 + l15] = acc5[i] + bv;
        }
    }
}

// ---------------------------------------------------------------------------
// CSR build (hist lives in prep_kernel)
__global__ __launch_bounds__(1024) void scan_block(const int* __restrict__ cnt,
                                                   int* __restrict__ off,
                                                   int* __restrict__ bsum, int n)
{
    __shared__ int tmp[1024];
    int tid = threadIdx.x;
    int i = blockIdx.x * 1024 + tid;
    int v = (i < n) ? cnt[i] : 0;
    tmp[tid] = v;
    __syncthreads();
    for (int s = 1; s < 1024; s <<= 1) {
        int t = (tid >= s) ? tmp[tid - s] : 0;
        __syncthreads();
        tmp[tid] += t;
        __syncthreads();
    }
    if (i < n) off[i] = tmp[tid] - v;
    if (tid == 1023) bsum[blockIdx.x] = tmp[1023];
}

__global__ void scan_add2(int* __restrict__ off, const int* __restrict__ bsum,
                          int n, int nb)
{
    __shared__ int pre[64];
    int tid = threadIdx.x;
    if (tid < 64) {
        int v = (tid < nb) ? bsum[tid] : 0;
        #pragma unroll
        for (int s = 1; s < 64; s <<= 1) {
            int t = __shfl_up(v, s);
            if (tid >= s) v += t;
        }
        pre[tid] = v;
    }
    __syncthreads();
    int i = blockIdx.x * blockDim.x + tid;
    if (i < n) {
        int chunk = i >> 10;
        off[i] += chunk ? pre[chunk - 1] : 0;
    }
    if (i == 0) off[n] = pre[nb - 1];
}

__global__ void scatter_kernel(const int* __restrict__ src, const int* __restrict__ dst,
                               const int* __restrict__ off, int* __restrict__ cnt,
                               int* __restrict__ csrc, int E)
{
    int e = blockIdx.x * blockDim.x + threadIdx.x;
    if (e < E) {
        int d = dst[e];
        int p = atomicSub(&cnt[d], 1) - 1;
        csrc[off[d] + p] = src[e];
    }
}

// ---------------------------------------------------------------------------
// Fused edge-softmax + weighted gather + bias + lrelu + head-mean.
// R20 structure (2 nodes/block, 384 thr, direct exp, 8-deep batch,
// barrier-free chunk loop) + R23 int8 gather: row = 384 B (3 heads x 128
// int8), per-(row,head) scale folded into edge weight; el+scale fetched in
// ONE float2 load from the combined ELS array. den uses unscaled w.
__global__ __launch_bounds__(384) void agg_kernel(
    const unsigned char* __restrict__ h8, const float* __restrict__ els,
    const float* __restrict__ er, const int* __restrict__ off,
    const int* __restrict__ csrc, const float* __restrict__ bias,
    short* __restrict__ outH, short* __restrict__ outL, int N)
{
    int tid = threadIdx.x;         // 0..383
    int u = tid >> 6;              // wave 0..5
    int nl = u / 3;                // node-local 0/1
    int head = u - nl * 3;         // 0..2
    int l = tid & 63;
    int n = blockIdx.x * 2 + nl;
    bool active = (n < N);

    __shared__ int   ssrcS[6][64];
    __shared__ float swS[6][64];
    __shared__ float smS[2][384];

    int beg = 0, deg = 0;
    float erv = 0.f;
    if (active) {
        beg = off[n];
        deg = off[n + 1] - beg;
        erv = er[n * 3 + head];
    }

    const unsigned char* hseg = h8 + head * 128 + l * 2;
    float ax = 0.f, ay = 0.f, denl = 0.f;

    for (int base = 0; base < deg; base += 64) {
        int cnt = min(64, deg - base);
        int s_l = 0; float w = 0.f, wS = 0.f;
        if (l < cnt) {
            s_l = csrc[beg + base + l];
            float2 e2 = *(const float2*)(els + (size_t)(s_l * 3 + head) * 2);
            float t = e2.x + erv;
            t = (t < 0.f) ? 0.2f * t : t;
            w = __expf(t);                 // direct exp: logits bounded
            wS = w * e2.y;                 // fold int8 scale into weight
        }
        denl += w;
        ssrcS[u][l] = s_l;                 // per-wave region: no barrier
        swS[u][l]   = wS;                  // (same-wave lgkmcnt ordering)
        for (int q0 = 0; q0 < cnt; q0 += 8) {
            int sA[8]; float wA[8]; unsigned vA[8];
            #pragma unroll
            for (int b = 0; b < 8; ++b) {
                int e = q0 + b;            // <= 63 always; pads have w=0,s=0
                sA[b] = ssrcS[u][e];
                wA[b] = swS[u][e];
            }
            #pragma unroll
            for (int b = 0; b < 8; ++b)
                vA[b] = *(const unsigned short*)(hseg + (size_t)sA[b] * 384);
            #pragma unroll
            for (int b = 0; b < 8; ++b) {
                int b0 = (int)(signed char)(vA[b] & 0xFF);
                int b1 = (int)(signed char)((vA[b] >> 8) & 0xFF);
                ax += wA[b] * (float)b0;
                ay += wA[b] * (float)b1;
            }
        }
    }

    float den = denl;
    #pragma unroll
    for (int msk = 1; msk < 64; msk <<= 1) den += __shfl_xor(den, msk);
    float r = 1.f / (den + 1e-9f);
    if (deg == 0) r = 0.f;

    if (active) {
        int fb = head * 128 + 2 * l;
        float2 bv = *(const float2*)(bias + fb);
        float vx = ax * r + bv.x; vx = (vx < 0.f) ? 0.01f * vx : vx;
        float vy = ay * r + bv.y; vy = (vy < 0.f) ? 0.01f * vy : vy;
        smS[nl][fb]     = vx;
        smS[nl][fb + 1] = vy;
    }
    __syncthreads();
    if (tid < 128) {
        int mn = tid >> 6;                 // node-local 0/1
        int n2 = blockIdx.x * 2 + mn;
        if (n2 < N) {
            int f0i = (tid & 63) * 2, f1i = f0i + 1;
            float mx = (smS[mn][f0i] + smS[mn][128 + f0i] + smS[mn][256 + f0i]) * (1.0f / 3.0f);
            float my = (smS[mn][f1i] + smS[mn][128 + f1i] + smS[mn][256 + f1i]) * (1.0f / 3.0f);
            short hx = f2bf(mx), lx = f2bf(mx - bf2f(hx));
            short hy = f2bf(my), ly = f2bf(my - bf2f(hy));
            unsigned ph = (unsigned)(unsigned short)hx | ((unsigned)(unsigned short)hy << 16);
            unsigned pl = (unsigned)(unsigned short)lx | ((unsigned)(unsigned short)ly << 16);
            *(unsigned*)(outH + (size_t)n2 * 128 + f0i) = ph;
            *(unsigned*)(outL + (size_t)n2 * 128 + f0i) = pl;
        }
    }
}

// ---------------------------------------------------------------------------
extern "C" void kernel_launch(void* const* d_in, const int* in_sizes, int n_in,
                              void* d_out, int out_size, void* d_ws, size_t ws_size,
                              hipStream_t stream)
{
    const float* in_feat = (const float*)d_in[0];
    const int*   src     = (const int*)d_in[1];
    const int*   dst     = (const int*)d_in[2];
    const float* W1  = (const float*)d_in[3];
    const float* al1 = (const float*)d_in[4];
    const float* ar1 = (const float*)d_in[5];
    const float* b1  = (const float*)d_in[6];
    const float* W2  = (const float*)d_in[7];
    const float* al2 = (const float*)d_in[8];
    const float* ar2 = (const float*)d_in[9];
    const float* b2  = (const float*)d_in[10];
    const float* lw1 = (const float*)d_in[11];
    const float* lb1 = (const float*)d_in[12];
    const float* lw2 = (const float*)d_in[13];
    const float* lb2 = (const float*)d_in[14];
    const float* lw3 = (const float*)d_in[15];
    const float* lb3 = (const float*)d_in[16];
    const float* lw4 = (const float*)d_in[17];
    const float* lb4 = (const float*)d_in[18];
    const float* lw5 = (const float*)d_in[19];
    const float* lb5 = (const float*)d_in[20];

    const int N = in_sizes[0] / 128;   // 50000
    const int E = in_sizes[1];         // 800000

    size_t o = 0;
    auto alloc = [&](size_t bytes) { size_t p = o; o = (o + bytes + 255) & ~(size_t)255; return p; };
    char* ws = (char*)d_ws;
    short* P1h = (short*)(ws + alloc((size_t)N * 128 * 2));
    short* P1l = (short*)(ws + alloc((size_t)N * 128 * 2));
    short* P2h = (short*)(ws + alloc((size_t)N * 128 * 2));
    short* P2l = (short*)(ws + alloc((size_t)N * 128 * 2));
    unsigned char* Aq = (unsigned char*)(ws + alloc((size_t)N * 384));   // int8 gemm out
    float* els = (float*)(ws + alloc((size_t)N * 3 * 2 * 4));            // {el, scale}
    float* er  = (float*)(ws + alloc((size_t)N * 3 * 4));
    int*   cnt  = (int*)(ws + alloc((size_t)N * 4));
    int*   off  = (int*)(ws + alloc((size_t)(N + 1) * 4));
    int*   bsum = (int*)(ws + alloc((size_t)4096));
    int*   csrc = (int*)(ws + alloc((size_t)E * 4));
    short* w1th = (short*)(ws + alloc((size_t)384 * 128 * 2));
    short* w1tl = (short*)(ws + alloc((size_t)384 * 128 * 2));
    short* w2th = (short*)(ws + alloc((size_t)384 * 128 * 2));
    short* w2tl = (short*)(ws + alloc((size_t)384 * 128 * 2));
    short* l1th = (short*)(ws + alloc((size_t)128 * 128 * 2));
    short* l1tl = (short*)(ws + alloc((size_t)128 * 128 * 2));
    short* l2th = (short*)(ws + alloc((size_t)128 * 128 * 2));
    short* l2tl = (short*)(ws + alloc((size_t)128 * 128 * 2));
    short* l3th = (short*)(ws + alloc((size_t)128 * 128 * 2));
    short* l3tl = (short*)(ws + alloc((size_t)128 * 128 * 2));
    short* l4th = (short*)(ws + alloc((size_t)128 * 128 * 2));
    short* l4tl = (short*)(ws + alloc((size_t)128 * 128 * 2));
    short* l5th = (short*)(ws + alloc((size_t)6 * 128 * 2));
    short* l5tl = (short*)(ws + alloc((size_t)6 * 128 * 2));
    (void)ws_size;

    float* out = (float*)d_out;

    // ---- fused prep: conv_split + weight transpose + hist (one launch)
    hipMemsetAsync(cnt, 0, (size_t)N * 4, stream);
    int n4 = N * 128 / 4;
    int cb = (n4 + 255) / 256;
    int wb = (164608 + 255) / 256;
    int hb = (E + 255) / 256;
    prep_kernel<<<cb + wb + hb, 256, 0, stream>>>(
        in_feat, P1h, P1l, n4, cb, wb, dst, cnt, E,
        W1, W2, lw1, lw2, lw3, lw4, lw5,
        w1th, w1tl, w2th, w2tl, l1th, l1tl, l2th, l2tl,
        l3th, l3tl, l4th, l4tl, l5th, l5tl);

    // ---- CSR scan + scatter
    int nb = (N + 1023) / 1024;
    scan_block<<<nb, 1024, 0, stream>>>(cnt, off, bsum, N);
    scan_add2<<<(N + 255) / 256, 256, 0, stream>>>(off, bsum, N, nb);
    scatter_kernel<<<(E + 255) / 256, 256, 0, stream>>>(src, dst, off, cnt, csrc, E);

    int RB = (N + BM - 1) / BM;
    dim3 ggrid(3, RB);
    int AGB = (N + 1) / 2;

    // ---- GAT layer 1 (int8 rowmax-scaled h for gather; exact fp32 el/er)
    gemm_mfma<<<ggrid, 256, 0, stream>>>(P1h, P1l, w1th, w1tl, Aq, els, er,
                                         al1, ar1, N, 384);
    agg_kernel<<<AGB, 384, 0, stream>>>(Aq, els, er, off, csrc, b1, P2h, P2l, N);

    // ---- GAT layer 2 (same int8 path)
    gemm_mfma<<<ggrid, 256, 0, stream>>>(P2h, P2l, w2th, w2tl, Aq, els, er,
                                         al2, ar2, N, 384);
    agg_kernel<<<AGB, 384, 0, stream>>>(Aq, els, er, off, csrc, b2, P1h, P1l, N);

    // ---- MLP head (fused lin1..lin5, 64-node blocks)
    int RBM = (N + MROWS - 1) / MROWS;
    mlp_fused<<<RBM, 256, 0, stream>>>(P1h, P1l,
                                       l1th, l1tl, l2th, l2tl, l3th, l3tl,
                                       l4th, l4tl, l5th, l5tl,
                                       lb1, lb2, lb3, lb4, lb5, out, N);
}